// Round 8
// baseline (1102.585 us; speedup 1.0000x reference)
//
#include <hip/hip_runtime.h>
#include <math.h>

// hipcc defaults to -ffp-contract=fast; contraction would fuse mul+add into
// FMA and break bit-exactness vs XLA. Scalar helpers use __fmul_rn/__fadd_rn
// (contraction-immune); pragma is belt+suspenders.
#pragma clang fp contract(off)

#define NSTEPS 3000
#define NWALK  1048576
#define BLOCK  256
#define NBD    (NWALK / BLOCK)   // 4096 blocks: one walker slot per lane
#define NDENSE 12                // dense rounds cover t in [0, 384)
#define CHUNK  32                // finer chunks: less mid-chunk dead-lane waste
#define NBT    2048              // tail grid: 8192 waves
#define NKEYS  3072

// Ping-pong survivor lists (i, p-bits), per-round counts, precomputed keys.
__device__ uint2    g_list[2][NWALK];
__device__ uint32_t g_cnt[16];
__device__ uint2    g_keys[NKEYS];

// Threefry-2x32, 20 rounds, exactly JAX's schedule. Rotates forced to
// v_alignbit_b32 (rotl(x,r) == alignbit(x,x,32-r)) — bitwise identical.
__device__ __forceinline__ void tf2x32(uint32_t k0, uint32_t k1,
                                       uint32_t x0, uint32_t x1,
                                       uint32_t& o0, uint32_t& o1) {
  uint32_t ks2 = k0 ^ k1 ^ 0x1BD11BDAu;
  x0 += k0; x1 += k1;
#define TFR(r) { x0 += x1; x1 = __builtin_amdgcn_alignbit(x1, x1, 32 - r); x1 ^= x0; }
  TFR(13) TFR(15) TFR(26) TFR(6)
  x0 += k1;  x1 += ks2 + 1u;
  TFR(17) TFR(29) TFR(16) TFR(24)
  x0 += ks2; x1 += k0 + 2u;
  TFR(13) TFR(15) TFR(26) TFR(6)
  x0 += k0;  x1 += k1 + 3u;
  TFR(17) TFR(29) TFR(16) TFR(24)
  x0 += k1;  x1 += ks2 + 4u;
  TFR(13) TFR(15) TFR(26) TFR(6)
  x0 += ks2; x1 += k0 + 5u;
#undef TFR
  o0 = x0; o1 = x1;
}

__global__ void init_kernel() {   // <<<NKEYS/256, 256>>>
  int t = blockIdx.x * 256 + threadIdx.x;
  uint32_t a, b;
  tf2x32(0u, 0u, 0u, (uint32_t)t, a, b);
  g_keys[t] = make_uint2(a, b);
  if (blockIdx.x == 0 && threadIdx.x < 16) g_cnt[threadIdx.x] = 0u;
}

// XLA CPU's log.f32 (Cephes/Eigen-3.3 plog), strict f32 mul/add, no FMA.
// Bit-exact vs reference (verified R3-R7: absmax 0.094 << 0.259).
__device__ __forceinline__ float xla_cpu_log_f32(float s) {
  uint32_t bits = __float_as_uint(s);
  int emm0 = (int)(bits >> 23) - 0x7f;
  float e = __fadd_rn((float)emm0, 1.0f);
  float m = __uint_as_float((bits & 0x007fffffu) | 0x3f000000u);
  bool mlt = m < 0.70710677f;
  float tmp = mlt ? m : 0.0f;
  float x = __fsub_rn(m, 1.0f);
  e = __fsub_rn(e, mlt ? 1.0f : 0.0f);
  x = __fadd_rn(x, tmp);
  float x2 = __fmul_rn(x, x);
  float x3 = __fmul_rn(x2, x);
  float y, y1, y2;
  y  = __fadd_rn(__fmul_rn(7.0376836292e-2f,  x), -1.1514610310e-1f);
  y1 = __fadd_rn(__fmul_rn(-1.2420140846e-1f, x),  1.4249322787e-1f);
  y2 = __fadd_rn(__fmul_rn(2.0000714765e-1f,  x), -2.4999993993e-1f);
  y  = __fadd_rn(__fmul_rn(y,  x),  1.1676998740e-1f);
  y1 = __fadd_rn(__fmul_rn(y1, x), -1.6668057665e-1f);
  y2 = __fadd_rn(__fmul_rn(y2, x),  3.3333331174e-1f);
  y  = __fadd_rn(__fmul_rn(y, x3), y1);
  y  = __fadd_rn(__fmul_rn(y, x3), y2);
  y  = __fmul_rn(y, x3);
  y1 = __fmul_rn(e, -2.12194440e-4f);
  tmp = __fmul_rn(x2, 0.5f);
  y  = __fadd_rn(y, y1);
  x  = __fsub_rn(x, tmp);
  y2 = __fmul_rn(e, 0.693359375f);
  x  = __fadd_rn(x, y);
  x  = __fadd_rn(x, y2);
  return x;
}

// XLA EmitErfInv f32 (Giles): w = -log((1-x)*(1+x)), branch at w<5.
// Branchy on purpose: when no lane of a wave takes the far tail (~5% of
// wave-steps), s_cbranch_execz skips the expensive sqrt_rn path.
__device__ __forceinline__ float xla_erfinv_f32(float x) {
  float s = __fmul_rn(__fsub_rn(1.0f, x), __fadd_rn(1.0f, x));
  float w = -xla_cpu_log_f32(s);
  float p;
  if (w < 5.0f) {
    float v = __fsub_rn(w, 2.5f);
    p = 2.81022636e-08f;
    p = __fadd_rn(__fmul_rn(p, v), 3.43273939e-07f);
    p = __fadd_rn(__fmul_rn(p, v), -3.5233877e-06f);
    p = __fadd_rn(__fmul_rn(p, v), -4.39150654e-06f);
    p = __fadd_rn(__fmul_rn(p, v), 0.00021858087f);
    p = __fadd_rn(__fmul_rn(p, v), -0.00125372503f);
    p = __fadd_rn(__fmul_rn(p, v), -0.00417768164f);
    p = __fadd_rn(__fmul_rn(p, v), 0.246640727f);
    p = __fadd_rn(__fmul_rn(p, v), 1.50140941f);
  } else {
    float v = __fsub_rn(__fsqrt_rn(w), 3.0f);
    p = -0.000200214257f;
    p = __fadd_rn(__fmul_rn(p, v), 0.000100950558f);
    p = __fadd_rn(__fmul_rn(p, v), 0.00134934322f);
    p = __fadd_rn(__fmul_rn(p, v), -0.00367342844f);
    p = __fadd_rn(__fmul_rn(p, v), 0.00573950773f);
    p = __fadd_rn(__fmul_rn(p, v), -0.0076224613f);
    p = __fadd_rn(__fmul_rn(p, v), 0.00943887047f);
    p = __fadd_rn(__fmul_rn(p, v), 1.00167406f);
    p = __fadd_rn(__fmul_rn(p, v), 2.83297682f);
  }
  return __fmul_rn(p, x);
}

__device__ __forceinline__ float normal_from_bits(uint32_t bits) {
  const float MINVAL = __uint_as_float(0xBF7FFFFFu);   // nextafter(-1,0)
  float f = __uint_as_float((bits >> 9) | 0x3F800000u) - 1.0f;
  float u = __fadd_rn(__fmul_rn(f, 2.0f), MINVAL);
  u = fmaxf(MINVAL, u);
  const float SQRT2 = __uint_as_float(0x3FB504F3u);
  return __fmul_rn(SQRT2, xla_erfinv_f32(u));
}

// Dense compaction round: one walker per lane, chunk [t0,t0+32). Branchless
// freeze (cndmask), no global stores in the loop; crossers write post-loop,
// survivors wave-aggregated-appended (one atomic per wave).
// __launch_bounds__(256,4): R7 proved 8 waves/SIMD saturates issue; relax
// the register allocator (R6/R7 squeezed to 16 VGPRs — suspected remat cost).
__global__ __launch_bounds__(BLOCK, 4)
void ddm_round(const float* __restrict__ sv_p, const float* __restrict__ rate_p,
               const float* __restrict__ ndt_p, const float* __restrict__ thr_p,
               const float* __restrict__ noise_p, const float* __restrict__ dt_p,
               const int* __restrict__ nw_p, float* __restrict__ out,
               int round, int t0) {
  __shared__ uint2 skeys[CHUNK];
  if (threadIdx.x < CHUNK) {
    uint32_t a, b;
    tf2x32(0u, 0u, 0u, (uint32_t)(t0 + threadIdx.x), a, b);
    skeys[threadIdx.x] = make_uint2(a, b);
  }
  __syncthreads();

  int nw = *nw_p;
  uint32_t count = (round == 0) ? (uint32_t)nw : g_cnt[round];
  uint32_t slot = blockIdx.x * BLOCK + threadIdx.x;
  bool in_range = slot < count;
  if (__ballot(in_range) == 0ull) return;

  float sv = *sv_p, rate = *rate_p, ndt = *ndt_p, thr = *thr_p,
        noise = *noise_p, dt = *dt_p;
  float rate_dt = __fmul_rn(rate, dt);
  float sqrt_dt = __fsqrt_rn(dt);
  int lane = threadIdx.x & 63;

  int i = 0; float p = 0.0f;
  if (in_range) {
    if (round == 0) { i = (int)slot; p = __fadd_rn(0.0f, sv); }
    else { uint2 e = g_list[round & 1][slot]; i = (int)e.x; p = __uint_as_float(e.y); }
  }
  bool alive = in_range;
  int r_idx = -1;

  for (int s = 0; s < CHUNK; ++s) {
    uint2 k = skeys[s];                    // wave-uniform: LDS broadcast
    uint32_t b1, b2;
    tf2x32(k.x, k.y, 0u, (uint32_t)i, b1, b2);
    float z = normal_from_bits(b1 ^ b2);
    float q = __fmul_rn(__fadd_rn(rate_dt, __fmul_rn(noise, z)), sqrt_dt);
    float pn = __fadd_rn(p, q);
    p = alive ? pn : p;                    // freeze after crossing
    bool c = alive & !(fabsf(p) < thr);
    r_idx = c ? s : r_idx;
    alive = alive & !c;
  }

  if (in_range & !alive) {                 // crossed this chunk
    float rts = (float)(t0 + r_idx + 1);   // exact int == accumulated +1.0f
    out[i] = __fadd_rn(ndt, __fmul_rn(rts, dt));
    out[nw + i] = (p <= -thr) ? 0.0f : 1.0f;
  }

  uint64_t m = __ballot(alive);
  if (m != 0ull) {                         // one atomic per wave; order-free
    int leader = __ffsll((unsigned long long)m) - 1;
    uint32_t base = 0;
    if (lane == leader) base = atomicAdd(&g_cnt[round + 1], (uint32_t)__popcll(m));
    base = (uint32_t)__shfl((int)base, leader);
    if (alive) {
      uint32_t pos = base + (uint32_t)__popcll(m & ((1ull << lane) - 1ull));
      g_list[(round + 1) & 1][pos] = make_uint2((uint32_t)i, __float_as_uint(p));
    }
  }
}

// Tail: one walker per wave; 64 q's in parallel per macro-step (counter-based
// RNG depends only on (t,i)), then exact wave-uniform sequential scan.
__global__ __launch_bounds__(BLOCK, 4)
void ddm_tail(const float* __restrict__ sv_p, const float* __restrict__ rate_p,
              const float* __restrict__ ndt_p, const float* __restrict__ thr_p,
              const float* __restrict__ noise_p, const float* __restrict__ dt_p,
              const int* __restrict__ nw_p, float* __restrict__ out,
              int round, int t0) {
  int nw = *nw_p;
  float rate = *rate_p, ndt = *ndt_p, thr = *thr_p,
        noise = *noise_p, dt = *dt_p;
  float rate_dt = __fmul_rn(rate, dt);
  float sqrt_dt = __fsqrt_rn(dt);

  int lane = threadIdx.x & 63;
  uint32_t wave = blockIdx.x * (BLOCK / 64) + (threadIdx.x >> 6);
  uint32_t nwaves = gridDim.x * (BLOCK / 64);
  uint32_t count = g_cnt[round];

  for (uint32_t k = wave; k < count; k += nwaves) {
    uint2 e = g_list[round & 1][k];
    int i = (int)e.x;
    float p = __uint_as_float(e.y);        // wave-uniform from here on
    int t = t0;
    int rts_i = NSTEPS;
    bool done = false;
    while (!done) {
      int valid = NSTEPS - t; if (valid > 64) valid = 64;
      int tl = t + (lane < valid ? lane : valid - 1);
      uint2 kk = g_keys[tl];
      uint32_t b1, b2;
      tf2x32(kk.x, kk.y, 0u, (uint32_t)i, b1, b2);
      float z = normal_from_bits(b1 ^ b2);
      float q = __fmul_rn(__fadd_rn(rate_dt, __fmul_rn(noise, z)), sqrt_dt);
      for (int j = 0; j < valid; ++j) {    // exact sequential scan (uniform)
        float qj = __shfl(q, j);
        p = __fadd_rn(p, qj);
        if (!(fabsf(p) < thr)) { rts_i = t + j + 1; done = true; break; }
      }
      if (!done) {
        t += valid;
        if (t >= NSTEPS) done = true;      // ran out the clock: rts = 3000
      }
    }
    if (lane == 0) {
      out[i] = __fadd_rn(ndt, __fmul_rn((float)rts_i, dt));
      out[nw + i] = (p <= -thr) ? 0.0f : 1.0f;
    }
  }
}

extern "C" void kernel_launch(void* const* d_in, const int* in_sizes, int n_in,
                              void* d_out, int out_size, void* d_ws, size_t ws_size,
                              hipStream_t stream) {
  const float* sv    = (const float*)d_in[0];
  const float* rate  = (const float*)d_in[1];
  const float* ndt   = (const float*)d_in[2];
  const float* thr   = (const float*)d_in[3];
  const float* noise = (const float*)d_in[4];
  const float* dt    = (const float*)d_in[5];
  const int*   nw    = (const int*)d_in[6];
  float* out = (float*)d_out;

  init_kernel<<<NKEYS / 256, 256, 0, stream>>>();
  for (int r = 0; r < NDENSE; ++r) {
    ddm_round<<<NBD, BLOCK, 0, stream>>>(sv, rate, ndt, thr, noise, dt, nw, out,
                                         r, r * CHUNK);
  }
  ddm_tail<<<NBT, BLOCK, 0, stream>>>(sv, rate, ndt, thr, noise, dt, nw, out,
                                      NDENSE, NDENSE * CHUNK);
}